// Round 3
// baseline (3435.540 us; speedup 1.0000x reference)
//
#include <hip/hip_runtime.h>
#include <stdint.h>

// RNN_60292750901480: h_t = tanh(x_t@Wx + b + h_{t-1}@Wh), N=128,T=512,D=H=512, fp32.
// Phase 1: xW = x@Wx+b via split-bf16 MFMA (fp32-quality) into d_out.
// Phase 2: persistent kernel, 8 row-clusters x 16 col-blocks, Wh B-frags in VGPRs.
// R2 -> R3: flag+data merged into one self-validating 8-byte word [tag|value].
//   - producer: just store; no drain-before-flag, no flag store
//   - consumer: poll the data words directly (per-lane), no wave0 spin + bcast barrier
//   - ring depth 2 is safe with NO extra sync: seeing tag==t from every peer implies
//     every peer finished READING slot t-2 (reads precede its publish of t-1)
//   - one __syncthreads per step (LDS reduce buffer double-buffered by t parity)

typedef __attribute__((ext_vector_type(8))) short short8;
typedef __attribute__((ext_vector_type(4))) float f32x4;

#define DEV static __device__ __forceinline__

DEV unsigned short f2bf(float f) {
    uint32_t u = __builtin_bit_cast(uint32_t, f);
    u += 0x7FFFu + ((u >> 16) & 1u);   // round-to-nearest-even
    return (unsigned short)(u >> 16);
}
DEV float bf2f(unsigned short h) {
    uint32_t u = ((uint32_t)h) << 16;
    return __builtin_bit_cast(float, u);
}
DEV void split8(const float* v, short8& hi, short8& lo) {
    #pragma unroll
    for (int j = 0; j < 8; ++j) {
        unsigned short h = f2bf(v[j]);
        float r = v[j] - bf2f(h);       // exact
        hi[j] = (short)h;
        lo[j] = (short)f2bf(r);
    }
}
// Truncation split: hi=trunc16(v), lo=trunc16(v-hi). hi+lo matches v to ~2^-16.
// Cheaper than RNE (no rounding add chain); used in the latency-critical scan.
DEV void split8t(const float* v, short8& hi, short8& lo) {
    #pragma unroll
    for (int j = 0; j < 8; ++j) {
        uint32_t u = __builtin_bit_cast(uint32_t, v[j]);
        float hif = __builtin_bit_cast(float, u & 0xFFFF0000u);
        hi[j] = (short)(u >> 16);
        float l = v[j] - hif;
        lo[j] = (short)(__builtin_bit_cast(uint32_t, l) >> 16);
    }
}

// ---------------- Phase 1: xW = x @ Wx + b  (M=65536, K=512, N=512) ----------------
__global__ __launch_bounds__(256) void xw_gemm(
    const float* __restrict__ x, const float* __restrict__ Wx,
    const float* __restrict__ bias, float* __restrict__ out)
{
    __shared__ short Ahi[128 * 32], Alo[128 * 32];
    __shared__ short Bhi[32 * 128], Blo[32 * 128];

    const int bid = blockIdx.x;
    const int m0 = (bid >> 2) * 128;
    const int n0 = (bid & 3) * 128;
    const int tid = threadIdx.x;
    const int lane = tid & 63;
    const int wave = tid >> 6;
    const int wr = (wave >> 1) * 64;
    const int wc = (wave & 1) * 64;

    f32x4 acc[4][4];
    #pragma unroll
    for (int i = 0; i < 4; ++i)
        #pragma unroll
        for (int j = 0; j < 4; ++j)
            acc[i][j] = (f32x4){0.f, 0.f, 0.f, 0.f};

    for (int kc = 0; kc < 512; kc += 32) {
        __syncthreads();
        #pragma unroll
        for (int cc = 0; cc < 2; ++cc) {
            int c = tid + cc * 256;
            int row = c >> 2, kb = c & 3;
            const float* src = x + (size_t)(m0 + row) * 512 + kc + kb * 8;
            alignas(16) float v[8];
            *(float4*)(v)     = *(const float4*)src;
            *(float4*)(v + 4) = *(const float4*)(src + 4);
            short8 h8, l8;
            split8(v, h8, l8);
            int cell = ((row >> 4) * 4 + kb) * 16 + (row & 15);
            *(short8*)&Ahi[cell * 8] = h8;
            *(short8*)&Alo[cell * 8] = l8;
        }
        {
            int cell = tid >> 3, j = tid & 7;
            int ct = cell >> 2, kb = cell & 3;
            const float* src = Wx + (size_t)(kc + kb * 8 + j) * 512 + n0 + ct * 16;
            #pragma unroll
            for (int c16 = 0; c16 < 16; ++c16) {
                float v = src[c16];
                unsigned short h = f2bf(v);
                int idx = (cell * 16 + c16) * 8 + j;
                Bhi[idx] = (short)h;
                Blo[idx] = (short)f2bf(v - bf2f(h));
            }
        }
        __syncthreads();

        short8 bh[4], bl[4];
        #pragma unroll
        for (int ct = 0; ct < 4; ++ct) {
            int CT = (wc >> 4) + ct;
            bh[ct] = *(const short8*)&Bhi[CT * 512 + lane * 8];
            bl[ct] = *(const short8*)&Blo[CT * 512 + lane * 8];
        }
        #pragma unroll
        for (int rt = 0; rt < 4; ++rt) {
            int RT = (wr >> 4) + rt;
            short8 ah = *(const short8*)&Ahi[RT * 512 + lane * 8];
            short8 al = *(const short8*)&Alo[RT * 512 + lane * 8];
            #pragma unroll
            for (int ct = 0; ct < 4; ++ct) {
                acc[rt][ct] = __builtin_amdgcn_mfma_f32_16x16x32_bf16(ah, bh[ct], acc[rt][ct], 0, 0, 0);
                acc[rt][ct] = __builtin_amdgcn_mfma_f32_16x16x32_bf16(al, bh[ct], acc[rt][ct], 0, 0, 0);
                acc[rt][ct] = __builtin_amdgcn_mfma_f32_16x16x32_bf16(ah, bl[ct], acc[rt][ct], 0, 0, 0);
            }
        }
    }
    #pragma unroll
    for (int ct = 0; ct < 4; ++ct) {
        int col = n0 + wc + ct * 16 + (lane & 15);
        float bv = bias[col];
        #pragma unroll
        for (int rt = 0; rt < 4; ++rt) {
            int rbase = m0 + wr + rt * 16 + (lane >> 4) * 4;
            #pragma unroll
            for (int j = 0; j < 4; ++j)
                out[(size_t)(rbase + j) * 512 + col] = acc[rt][ct][j] + bv;
        }
    }
}

// ---------------- Phase 2: persistent recurrence ----------------
// 128 wgs: cluster r = b&7 (16 batch rows), col-block c = b>>3 (32 cols).
// Mailbox: 2-deep ring of [128 rows][512 cols] of uint64 {tag:32 | fp32:32}.
// h_t stored in slot t&1 with tag t+1 (poison 0xAAAAAAAA never matches a tag).
__global__ __launch_bounds__(256) void rnn_scan(
    float* xw_out,                      // d_out: xW in, h out (aliased by design)
    const float* __restrict__ h0,
    const float* __restrict__ Wh,
    unsigned long long* __restrict__ mbox)  // [2][128][512] in d_ws
{
    const int b = blockIdx.x;
    const int r = b & 7;
    const int cblk = b >> 3;
    const int tid = threadIdx.x;
    const int lane = tid & 63;
    const int wave = tid >> 6;
    const int m0 = r * 16;
    const int n0 = cblk * 32;
    const int k0 = wave * 128;

    // Preload Wh B-fragments (hi/lo), resident across all 512 steps.
    short8 Bh[4][2], Bl[4][2];
    #pragma unroll
    for (int s = 0; s < 4; ++s) {
        #pragma unroll
        for (int ct = 0; ct < 2; ++ct) {
            int col = n0 + ct * 16 + (lane & 15);
            #pragma unroll
            for (int j = 0; j < 8; ++j) {
                int k = k0 + s * 32 + (lane >> 4) * 8 + j;
                float v = Wh[(size_t)k * 512 + col];
                unsigned short h = f2bf(v);
                Bh[s][ct][j] = (short)h;
                Bl[s][ct][j] = (short)f2bf(v - bf2f(h));
            }
        }
    }

    __shared__ float red[2][4][2][16][16]; // [t&1][wave][coltile][row][col]

    const int erow = tid >> 5;           // 0..7
    const int ecol = tid & 31;           // 0..31
    const int arow = lane & 15, akb = lane >> 4;

    for (int t = 0; t < 512; ++t) {
        // Prefetch this step's xW tile (plain cached loads; wg-private slice)
        size_t xi0 = ((size_t)(m0 + erow) * 512 + t) * 512 + n0 + ecol;
        size_t xi1 = ((size_t)(m0 + 8 + erow) * 512 + t) * 512 + n0 + ecol;
        float xw0 = xw_out[xi0];
        float xw1 = xw_out[xi1];

        // ---- acquire h_{t-1}: per-lane self-validating mailbox poll ----
        alignas(16) float hv[4][8];
        if (t == 0) {
            #pragma unroll
            for (int s = 0; s < 4; ++s) {
                const float* ap = h0 + (size_t)(m0 + arow) * 512 + k0 + s * 32 + akb * 8;
                #pragma unroll
                for (int j = 0; j < 8; ++j) hv[s][j] = ap[j];
            }
        } else {
            const unsigned long long* base =
                mbox + (size_t)(((t - 1) & 1) * 128 + m0 + arow) * 512 + k0 + akb * 8;
            unsigned long long w[4][8];
            #pragma unroll
            for (int s = 0; s < 4; ++s)
                #pragma unroll
                for (int j = 0; j < 8; ++j)
                    w[s][j] = __hip_atomic_load(&base[s * 32 + j], __ATOMIC_RELAXED,
                                                __HIP_MEMORY_SCOPE_AGENT);
            const unsigned want = (unsigned)t;   // h_{t-1} tagged t
            for (;;) {
                unsigned stale = 0u;
                #pragma unroll
                for (int s = 0; s < 4; ++s)
                    #pragma unroll
                    for (int j = 0; j < 8; ++j)
                        if ((unsigned)(w[s][j] >> 32) != want) stale |= 1u << (s * 8 + j);
                if (!stale) break;
                #pragma unroll
                for (int s = 0; s < 4; ++s)
                    #pragma unroll
                    for (int j = 0; j < 8; ++j)
                        if (stale & (1u << (s * 8 + j)))
                            w[s][j] = __hip_atomic_load(&base[s * 32 + j], __ATOMIC_RELAXED,
                                                        __HIP_MEMORY_SCOPE_AGENT);
            }
            #pragma unroll
            for (int s = 0; s < 4; ++s)
                #pragma unroll
                for (int j = 0; j < 8; ++j)
                    hv[s][j] = __builtin_bit_cast(float, (uint32_t)w[s][j]);
        }

        // ---- split-bf16 MFMA, k-split 128/wave ----
        f32x4 acc0 = (f32x4){0.f, 0.f, 0.f, 0.f};
        f32x4 acc1 = (f32x4){0.f, 0.f, 0.f, 0.f};
        #pragma unroll
        for (int s = 0; s < 4; ++s) {
            short8 ah, al;
            split8t(hv[s], ah, al);
            acc0 = __builtin_amdgcn_mfma_f32_16x16x32_bf16(ah, Bh[s][0], acc0, 0, 0, 0);
            acc0 = __builtin_amdgcn_mfma_f32_16x16x32_bf16(al, Bh[s][0], acc0, 0, 0, 0);
            acc0 = __builtin_amdgcn_mfma_f32_16x16x32_bf16(ah, Bl[s][0], acc0, 0, 0, 0);
            acc1 = __builtin_amdgcn_mfma_f32_16x16x32_bf16(ah, Bh[s][1], acc1, 0, 0, 0);
            acc1 = __builtin_amdgcn_mfma_f32_16x16x32_bf16(al, Bh[s][1], acc1, 0, 0, 0);
            acc1 = __builtin_amdgcn_mfma_f32_16x16x32_bf16(ah, Bl[s][1], acc1, 0, 0, 0);
        }

        // ---- k-split reduction across 4 waves (double-buffered by t parity) ----
        const int p = t & 1;
        #pragma unroll
        for (int ct = 0; ct < 2; ++ct) {
            f32x4 a = ct ? acc1 : acc0;
            #pragma unroll
            for (int j = 0; j < 4; ++j)
                red[p][wave][ct][(lane >> 4) * 4 + j][lane & 15] = a[j];
        }
        __syncthreads();   // the ONLY barrier per step

        int ctt = ecol >> 4, c16 = ecol & 15;
        float sum0 = red[p][0][ctt][erow][c16] + red[p][1][ctt][erow][c16]
                   + red[p][2][ctt][erow][c16] + red[p][3][ctt][erow][c16];
        float sum1 = red[p][0][ctt][erow + 8][c16] + red[p][1][ctt][erow + 8][c16]
                   + red[p][2][ctt][erow + 8][c16] + red[p][3][ctt][erow + 8][c16];
        float hv0 = tanhf(xw0 + sum0);
        float hv1 = tanhf(xw1 + sum1);

        xw_out[xi0] = hv0;                       // final output [N,T,H] (plain)
        xw_out[xi1] = hv1;

        // ---- publish h_t: value+tag in one 8-byte atomic word; no fence/flag ----
        const unsigned long long tag = ((unsigned long long)(t + 1)) << 32;
        unsigned long long* mb = mbox + (size_t)(p * 128) * 512;
        __hip_atomic_store(&mb[(size_t)(m0 + erow) * 512 + n0 + ecol],
                           tag | (unsigned long long)__builtin_bit_cast(uint32_t, hv0),
                           __ATOMIC_RELAXED, __HIP_MEMORY_SCOPE_AGENT);
        __hip_atomic_store(&mb[(size_t)(m0 + 8 + erow) * 512 + n0 + ecol],
                           tag | (unsigned long long)__builtin_bit_cast(uint32_t, hv1),
                           __ATOMIC_RELAXED, __HIP_MEMORY_SCOPE_AGENT);
        // No trailing barrier: next step's mailbox poll enforces both intra- and
        // inter-wg ordering (a wave can only see tag t+1 everywhere after every
        // peer - including own-wg waves - finished reading slot t-1).
    }
}

extern "C" void kernel_launch(void* const* d_in, const int* in_sizes, int n_in,
                              void* d_out, int out_size, void* d_ws, size_t ws_size,
                              hipStream_t stream)
{
    const float* x  = (const float*)d_in[0];
    const float* h0 = (const float*)d_in[1];
    const float* Wx = (const float*)d_in[2];
    const float* Wh = (const float*)d_in[3];
    const float* b  = (const float*)d_in[4];
    float* out = (float*)d_out;

    unsigned long long* mbox = (unsigned long long*)d_ws;   // 1 MiB ring

    hipLaunchKernelGGL(xw_gemm, dim3(2048), dim3(256), 0, stream, x, Wx, b, out);
    hipLaunchKernelGGL(rnn_scan, dim3(128), dim3(256), 0, stream, out, h0, Wh, mbox);
}